// Round 10
// baseline (322.629 us; speedup 1.0000x reference)
//
#include <hip/hip_runtime.h>
#include <math.h>

typedef unsigned short u16;
typedef short bf16x8 __attribute__((ext_vector_type(8)));
typedef float f32x4 __attribute__((ext_vector_type(4)));

#define NRAYS 4096
#define NSAMP 128
#define NPTS (NRAYS * NSAMP)
#define TBL_MASK 0x7FFFFu
#define LVL_STRIDE (524288 * 2)

// d_ws u16-element offsets
#define W0H  0        // [64][32] h
#define W0M  2048     // [64][32] m
#define W1H  4096     // [64][64] h
#define W1M  8192     // [64][64] m
#define WBG  12288    // [16][64] plain bf16 W2 (geo)
#define WBC0 13312    // [64][64] remapped rows
#define WBC1 17408
#define WBC2 21504
#define WBC3 25600    // [16][64]
#define W2C0_OFF 57344   // byte offset: f32[64] = ws2 column 0
#define RAW_OFF 131072   // byte offset of raw (bf16x4/point = 4 MB)

#define MEMBAR() asm volatile("" ::: "memory")

struct ResArr { float r[16]; };

__device__ __forceinline__ u16 f2b(float f) {   // RNE f32->bf16
  unsigned u = __float_as_uint(f);
  unsigned r = u + 0x7FFFu + ((u >> 16) & 1u);
  return (u16)(r >> 16);
}
__device__ __forceinline__ unsigned pack2(float lo, float hi) {
  return (unsigned)f2b(lo) | ((unsigned)f2b(hi) << 16);
}
__device__ __forceinline__ float b2f(u16 u) {
  return __uint_as_float(((unsigned)u) << 16);
}
// 8 channels (two float4) -> 2-way split fragments (h, m)
__device__ __forceinline__ void split2_8(float4 a, float4 b, bf16x8& H, bf16x8& M) {
  float v[8] = {a.x, a.y, a.z, a.w, b.x, b.y, b.z, b.w};
  #pragma unroll
  for (int e = 0; e < 8; ++e) {
    u16 h = f2b(v[e]);
    H[e] = (short)h;
    M[e] = (short)f2b(v[e] - b2f(h));    // exact residual (Sterbenz)
  }
}
__device__ __forceinline__ bf16x8 tob8(float4 a, float4 b) {
  bf16x8 r;
  r[0] = (short)f2b(a.x); r[1] = (short)f2b(a.y); r[2] = (short)f2b(a.z); r[3] = (short)f2b(a.w);
  r[4] = (short)f2b(b.x); r[5] = (short)f2b(b.y); r[6] = (short)f2b(b.z); r[7] = (short)f2b(b.w);
  return r;
}
__device__ __forceinline__ float sigmoidf_(float x) { return 1.f / (1.f + expf(-x)); }

// ---------------- prep: probe k-map, 2-way-split sigma w, pack color w ----------------
__global__ void __launch_bounds__(256)
prep_kernel(const float* __restrict__ ws0, const float* __restrict__ ws1,
            const float* __restrict__ ws2, const float* __restrict__ wc0,
            const float* __restrict__ wc1, const float* __restrict__ wc2,
            const float* __restrict__ wc3, u16* __restrict__ wb,
            float* __restrict__ w2c0)
{
  __shared__ int P[32];
  __shared__ int Pinv[32];
  const int t = threadIdx.x;
  if (t < 64) {
    const int g = t >> 4;
    for (int tt = 0; tt < 32; ++tt) {
      bf16x8 A, B;
      #pragma unroll
      for (int e = 0; e < 8; ++e) {
        A[e] = (short)f2b((float)(g * 8 + e + 1));
        B[e] = (short)((g * 8 + e == tt) ? 0x3F80 : 0);
      }
      f32x4 c = {0.f, 0.f, 0.f, 0.f};
      c = __builtin_amdgcn_mfma_f32_16x16x32_bf16(A, B, c, 0, 0, 0);
      if (t == 0) P[tt] = (int)(c[0] + 0.5f) - 1;
    }
  }
  __syncthreads();
  if (t < 32) Pinv[t] = t;
  __syncthreads();
  if (t < 32) { int p = P[t]; if (p >= 0 && p < 32) Pinv[p] = t; }
  __syncthreads();

  const int gt = blockIdx.x * 256 + t;
  const int GS = 8 * 256;
  for (int i = gt; i < 2048; i += GS) {          // W0 [64][32] h/m
    int o = i >> 5, k = i & 31, kt = Pinv[k];
    float v = ws0[kt * 64 + o];
    u16 h = f2b(v);
    wb[W0H + i] = h; wb[W0M + i] = f2b(v - b2f(h));
  }
  for (int i = gt; i < 4096; i += GS) {          // W1 [64][64] h/m
    int o = i >> 6, k = i & 63, kt = (k & 32) | Pinv[k & 31];
    float v = ws1[kt * 64 + o];
    u16 h = f2b(v);
    wb[W1H + i] = h; wb[W1M + i] = f2b(v - b2f(h));
  }
  for (int i = gt; i < 1024; i += GS) {          // W2 geo plain bf16 [16][64]
    int o = i >> 6, s = i & 63, kt = (s & 32) | Pinv[s & 31];
    wb[WBG + i] = f2b(ws2[kt * 16 + o]);
  }
  for (int i = gt; i < 64; i += GS) w2c0[i] = ws2[i * 16];   // sigma col f32
  // color layer 0: cin slots 0..15 encd, 16 dead(sigma), 17..31 geo(1..15),
  // 32..47 app, 48..63 zero
  for (int i = gt; i < 4096; i += GS) {
    int o = i >> 6, s = i & 63, kt = (s & 32) | Pinv[s & 31];
    float v = 0.f;
    if (kt < 16) v = wc0[kt * 64 + o];
    else if (kt >= 17 && kt <= 47) v = wc0[(kt - 1) * 64 + o];
    wb[WBC0 + i] = f2b(v);
  }
  for (int i = gt; i < 4096; i += GS) {
    int o = i >> 6, s = i & 63, kt = (s & 32) | Pinv[s & 31];
    wb[WBC1 + i] = f2b(wc1[kt * 64 + o]);
  }
  for (int i = gt; i < 4096; i += GS) {
    int o = i >> 6, s = i & 63, kt = (s & 32) | Pinv[s & 31];
    wb[WBC2 + i] = f2b(wc2[kt * 64 + o]);
  }
  for (int i = gt; i < 1024; i += GS) {
    int o = i >> 6, s = i & 63, kt = (s & 32) | Pinv[s & 31];
    wb[WBC3 + i] = f2b(o < 3 ? wc3[kt * 3 + o] : 0.f);
  }
}

// ---------------- fused encode + half-tile split-MFMA sigma + bf16 color ----------------
// 1 wave/block. LDS: EC 8KB + HB 2KB = 10240 B -> 16 blocks/CU (= 4 waves/EU).
// Occupancy control via attributes ONLY: waves_per_eu(2,4) -- max=4 stops the
// allocator from targeting 8 waves/EU (R8/R9 lesson: launch_bounds(64,4) emits
// min-only -> compiler squeezed to 64 VGPR + 244MB scratch spill).
// Encode streams each level's float2 straight to LDS (no encp[32] array).
__global__ __attribute__((amdgpu_flat_work_group_size(64, 64), amdgpu_waves_per_eu(2, 4)))
void point_kernel(const float* __restrict__ rays, const float* __restrict__ tables,
                  const u16* __restrict__ wb, const float* __restrict__ w2c0,
                  const float* __restrict__ app_table, u16* __restrict__ raw, ResArr RES)
{
  __shared__ char lds[10240];
  char* EC = lds;
  char* HB = lds + 8192;
  const int lane = threadIdx.x;
  const int pBase = blockIdx.x * 64;
  const int q = lane & 15, g = lane >> 4;
  const unsigned swzQ = (unsigned)((q & 7) << 4);
  const unsigned swzMy = (unsigned)((lane & 7) << 4);

  // ---------- phase 1: per-thread hash encode (streamed to LDS) ----------
  const int ptG = pBase + lane;
  const int r = ptG >> 7, s = ptG & (NSAMP - 1);
  const float ox = rays[r * 7 + 0], oy = rays[r * 7 + 1], oz = rays[r * 7 + 2];
  const float dx = rays[r * 7 + 3], dy = rays[r * 7 + 4], dz = rays[r * 7 + 5];
  const int code = (int)rays[r * 7 + 6];
  const float z = 0.5f + (3.5f / 127.f) * (float)s;
  const float x = fmaf(dx, z, ox), y = fmaf(dy, z, oy), w = fmaf(dz, z, oz);
  const bool keep = (x >= -4.f && x <= 4.f && y >= -4.f && y <= 4.f &&
                     w >= -4.f && w <= 4.f);
  const float keepf = keep ? 1.f : 0.f;
  const float xc = fminf(fmaxf(x, -4.f), 4.f);
  const float yc = fminf(fmaxf(y, -4.f), 4.f);
  const float zc = fminf(fmaxf(w, -4.f), 4.f);

  #pragma unroll
  for (int l = 0; l < 16; ++l) {
    const float res = RES.r[l];
    const float sc = res * 0.125f;
    const float px = (xc + 4.f) * sc, py = (yc + 4.f) * sc, pz = (zc + 4.f) * sc;
    const float bx = floorf(px), by = floorf(py), bz = floorf(pz);
    const float fx = px - bx, fy = py - by, fz = pz - bz;
    const unsigned ix = (unsigned)bx, iy = (unsigned)by, iz = (unsigned)bz;
    const unsigned hx0 = ix, hx1 = ix + 1u;
    const unsigned hy0 = iy * 2654435761u, hy1 = (iy + 1u) * 2654435761u;
    const unsigned hz0 = iz * 805459861u,  hz1 = (iz + 1u) * 805459861u;
    const float wx0 = 1.f - fx, wy0 = 1.f - fy, wz0 = 1.f - fz;
    const float* tl = tables + (size_t)l * LVL_STRIDE;
    float f0 = 0.f, f1 = 0.f;
    #pragma unroll
    for (int c = 0; c < 8; ++c) {
      const unsigned cx = (c >> 2) & 1, cy = (c >> 1) & 1, cz = c & 1;
      const unsigned idx = ((cx ? hx1 : hx0) ^ (cy ? hy1 : hy0) ^ (cz ? hz1 : hz0)) & TBL_MASK;
      const float cw = (cx ? fx : wx0) * (cy ? fy : wy0) * (cz ? fz : wz0);
      const float2 e = *reinterpret_cast<const float2*>(tl + (size_t)idx * 2);
      f0 = fmaf(cw, e.x, f0);
      f1 = fmaf(cw, e.y, f1);
    }
    // stream channels 2l, 2l+1 straight to own EC row (swz bits 4-6, bit 3 free)
    *(float2*)(EC + lane * 128 + (((unsigned)(l * 8)) ^ swzMy)) = make_float2(f0, f1);
  }
  MEMBAR();

  // 4-product 2-way-split accumulate (hh, mh, hm, mm)
  auto four = [&](const u16* pH, const u16* pM, bf16x8 bh, bf16x8 bm, f32x4 c) -> f32x4 {
    bf16x8 Ah = *(const bf16x8*)pH, Am = *(const bf16x8*)pM;
    c = __builtin_amdgcn_mfma_f32_16x16x32_bf16(Ah, bh, c, 0, 0, 0);
    c = __builtin_amdgcn_mfma_f32_16x16x32_bf16(Am, bh, c, 0, 0, 0);
    c = __builtin_amdgcn_mfma_f32_16x16x32_bf16(Ah, bm, c, 0, 0, 0);
    c = __builtin_amdgcn_mfma_f32_16x16x32_bf16(Am, bm, c, 0, 0, 0);
    return c;
  };
  // store C half-tile (lane q,g holds ch (m&1)*16+g*4..+3 of point-col q) into HB
  auto stH = [&](int mh, f32x4 c, bool relu) {
    if (relu) {
      c[0] = fmaxf(c[0], 0.f); c[1] = fmaxf(c[1], 0.f);
      c[2] = fmaxf(c[2], 0.f); c[3] = fmaxf(c[3], 0.f);
    }
    *(float4*)(HB + q * 128 + (((unsigned)(mh * 64 + g * 16)) ^ swzQ)) =
        make_float4(c[0], c[1], c[2], c[3]);
  };

  // ---------- phase 2: sigma MLP, per-n, half-tile ping-pong in HB ----------
  float sigv[4];
  #pragma unroll
  for (int n = 0; n < 4; ++n) {
    // B0: 2-way split of enc row (n*16+q)
    bf16x8 B0h, B0m;
    {
      const char* p = EC + (n * 16 + q) * 128;
      float4 a = *(const float4*)(p + (((unsigned)(g * 32)) ^ swzQ));
      float4 b = *(const float4*)(p + (((unsigned)(g * 32 + 16)) ^ swzQ));
      split2_8(a, b, B0h, B0m);
    }
    f32x4 acc1[4];
    #pragma unroll
    for (int m = 0; m < 4; ++m) acc1[m] = f32x4{0.f, 0.f, 0.f, 0.f};

    // L0 half a (h1 ch 0..31) -> HB
    #pragma unroll
    for (int m = 0; m < 2; ++m) {
      const int row = (m * 16 + q) * 32 + g * 8;
      f32x4 c = {0.f, 0.f, 0.f, 0.f};
      c = four(wb + W0H + row, wb + W0M + row, B0h, B0m, c);
      stH(m, c, true);
    }
    MEMBAR();
    // L1 kc=0
    {
      float4 a = *(const float4*)(HB + q * 128 + (((unsigned)(g * 32)) ^ swzQ));
      float4 b = *(const float4*)(HB + q * 128 + (((unsigned)(g * 32 + 16)) ^ swzQ));
      bf16x8 Bh, Bm; split2_8(a, b, Bh, Bm);
      #pragma unroll
      for (int m = 0; m < 4; ++m) {
        const int row = (m * 16 + q) * 64 + g * 8;
        acc1[m] = four(wb + W1H + row, wb + W1M + row, Bh, Bm, acc1[m]);
      }
    }
    MEMBAR();
    // L0 half b (h1 ch 32..63) -> HB
    #pragma unroll
    for (int m = 2; m < 4; ++m) {
      const int row = (m * 16 + q) * 32 + g * 8;
      f32x4 c = {0.f, 0.f, 0.f, 0.f};
      c = four(wb + W0H + row, wb + W0M + row, B0h, B0m, c);
      stH(m & 1, c, true);
    }
    MEMBAR();
    // L1 kc=1
    {
      float4 a = *(const float4*)(HB + q * 128 + (((unsigned)(g * 32)) ^ swzQ));
      float4 b = *(const float4*)(HB + q * 128 + (((unsigned)(g * 32 + 16)) ^ swzQ));
      bf16x8 Bh, Bm; split2_8(a, b, Bh, Bm);
      #pragma unroll
      for (int m = 0; m < 4; ++m) {
        const int row = (m * 16 + q) * 64 + 32 + g * 8;
        acc1[m] = four(wb + W1H + row, wb + W1M + row, Bh, Bm, acc1[m]);
      }
    }
    #pragma unroll
    for (int m = 0; m < 4; ++m) {
      acc1[m][0] = fmaxf(acc1[m][0], 0.f); acc1[m][1] = fmaxf(acc1[m][1], 0.f);
      acc1[m][2] = fmaxf(acc1[m][2], 0.f); acc1[m][3] = fmaxf(acc1[m][3], 0.f);
    }
    MEMBAR();
    // L2: geo (plain bf16) + sigma dot (f32), via the same half-tile HB
    f32x4 gc = {0.f, 0.f, 0.f, 0.f};
    float sp = 0.f;
    stH(0, acc1[0], false); stH(1, acc1[1], false);
    MEMBAR();
    {
      float4 a = *(const float4*)(HB + q * 128 + (((unsigned)(g * 32)) ^ swzQ));
      float4 b = *(const float4*)(HB + q * 128 + (((unsigned)(g * 32 + 16)) ^ swzQ));
      bf16x8 Bg = tob8(a, b);
      gc = __builtin_amdgcn_mfma_f32_16x16x32_bf16(
          *(const bf16x8*)(wb + WBG + q * 64 + g * 8), Bg, gc, 0, 0, 0);
      float4 wa = *(const float4*)(w2c0 + g * 8);
      float4 wb4 = *(const float4*)(w2c0 + g * 8 + 4);
      sp = fmaf(a.x, wa.x, sp); sp = fmaf(a.y, wa.y, sp);
      sp = fmaf(a.z, wa.z, sp); sp = fmaf(a.w, wa.w, sp);
      sp = fmaf(b.x, wb4.x, sp); sp = fmaf(b.y, wb4.y, sp);
      sp = fmaf(b.z, wb4.z, sp); sp = fmaf(b.w, wb4.w, sp);
    }
    MEMBAR();
    stH(0, acc1[2], false); stH(1, acc1[3], false);
    MEMBAR();
    {
      float4 a = *(const float4*)(HB + q * 128 + (((unsigned)(g * 32)) ^ swzQ));
      float4 b = *(const float4*)(HB + q * 128 + (((unsigned)(g * 32 + 16)) ^ swzQ));
      bf16x8 Bg = tob8(a, b);
      gc = __builtin_amdgcn_mfma_f32_16x16x32_bf16(
          *(const bf16x8*)(wb + WBG + q * 64 + 32 + g * 8), Bg, gc, 0, 0, 0);
      float4 wa = *(const float4*)(w2c0 + 32 + g * 8);
      float4 wb4 = *(const float4*)(w2c0 + 32 + g * 8 + 4);
      sp = fmaf(a.x, wa.x, sp); sp = fmaf(a.y, wa.y, sp);
      sp = fmaf(a.z, wa.z, sp); sp = fmaf(a.w, wa.w, sp);
      sp = fmaf(b.x, wb4.x, sp); sp = fmaf(b.y, wb4.y, sp);
      sp = fmaf(b.z, wb4.z, sp); sp = fmaf(b.w, wb4.w, sp);
    }
    // geo (no relu) -> color slots 16+4g..19+4g of row n*16+q (slot16 weight=0)
    {
      uint2 u; u.x = pack2(gc[0], gc[1]); u.y = pack2(gc[2], gc[3]);
      *(uint2*)(EC + (n * 16 + q) * 128 + (((unsigned)(32 + 8 * g)) ^ swzQ)) = u;
    }
    sp += __shfl_xor(sp, 16);
    sp += __shfl_xor(sp, 32);
    sigv[n] = sp * __shfl(keepf, n * 16 + q);
    MEMBAR();
  }

  // own row: encd slots 0..15, app 32..47, zeros 48..63
  {
    const float xx = dx * dx, yy = dy * dy, zz2 = dz * dz;
    const float xy = dx * dy, yz = dy * dz, xz = dx * dz;
    float e0 = 0.28209479177387814f;
    float e1 = -0.4886025119029199f * dy;
    float e2 = 0.4886025119029199f * dz;
    float e3 = -0.4886025119029199f * dx;
    float e4 = 1.0925484305920792f * xy;
    float e5 = -1.0925484305920792f * yz;
    float e6 = 0.31539156525252005f * (2.f * zz2 - xx - yy);
    float e7 = -1.0925484305920792f * xz;
    float e8 = 0.5462742152960396f * (xx - yy);
    float e9 = -0.5900435899266435f * dy * (3.f * xx - yy);
    float e10 = 2.890611442640554f * xy * dz;
    float e11 = -0.4570457994644658f * dy * (4.f * zz2 - xx - yy);
    float e12 = 0.3731763325901154f * dz * (2.f * zz2 - 3.f * xx - 3.f * yy);
    float e13 = -0.4570457994644658f * dx * (4.f * zz2 - xx - yy);
    float e14 = 1.445305721320277f * dz * (xx - yy);
    float e15 = -0.5900435899266435f * dx * (xx - 3.f * yy);
    uint4 u0; u0.x = pack2(e0, e1);  u0.y = pack2(e2, e3);  u0.z = pack2(e4, e5);  u0.w = pack2(e6, e7);
    uint4 u1; u1.x = pack2(e8, e9);  u1.y = pack2(e10, e11); u1.z = pack2(e12, e13); u1.w = pack2(e14, e15);
    *(uint4*)(EC + lane * 128 + (0u ^ swzMy)) = u0;
    *(uint4*)(EC + lane * 128 + (16u ^ swzMy)) = u1;
    const float4* ap = (const float4*)(app_table + (size_t)code * 16);
    float4 a0 = ap[0], a1 = ap[1], a2 = ap[2], a3 = ap[3];
    uint4 v0; v0.x = pack2(a0.x, a0.y); v0.y = pack2(a0.z, a0.w); v0.z = pack2(a1.x, a1.y); v0.w = pack2(a1.z, a1.w);
    uint4 v1; v1.x = pack2(a2.x, a2.y); v1.y = pack2(a2.z, a2.w); v1.z = pack2(a3.x, a3.y); v1.w = pack2(a3.z, a3.w);
    *(uint4*)(EC + lane * 128 + (64u ^ swzMy)) = v0;
    *(uint4*)(EC + lane * 128 + (80u ^ swzMy)) = v1;
    uint4 zv; zv.x = 0u; zv.y = 0u; zv.z = 0u; zv.w = 0u;
    *(uint4*)(EC + lane * 128 + (96u ^ swzMy)) = zv;
    *(uint4*)(EC + lane * 128 + (112u ^ swzMy)) = zv;
  }
  MEMBAR();

  // ---------- phase 3: color MFMA MLP (plain bf16, proven) ----------
  auto rdB = [&](int n, int kc) -> bf16x8 {
    return *(const bf16x8*)(EC + (n * 16 + q) * 128 + (((unsigned)(kc * 64 + g * 16)) ^ swzQ));
  };
  auto ldA = [&](const u16* Wp, int row, int kc) -> bf16x8 {
    return *(const bf16x8*)(Wp + row * 64 + kc * 32 + g * 8);
  };
  auto wrC = [&](int n, int slot0, f32x4 c) {
    c[0] = fmaxf(c[0], 0.f); c[1] = fmaxf(c[1], 0.f);
    c[2] = fmaxf(c[2], 0.f); c[3] = fmaxf(c[3], 0.f);
    uint2 u; u.x = pack2(c[0], c[1]); u.y = pack2(c[2], c[3]);
    *(uint2*)(EC + (n * 16 + q) * 128 + (((unsigned)(slot0 * 2)) ^ swzQ)) = u;
  };
  auto layer64 = [&](const u16* Wp) {
    bf16x8 A[4][2];
    #pragma unroll
    for (int m = 0; m < 4; ++m) {
      A[m][0] = ldA(Wp, m * 16 + q, 0);
      A[m][1] = ldA(Wp, m * 16 + q, 1);
    }
    #pragma unroll
    for (int n = 0; n < 4; ++n) {
      bf16x8 b0 = rdB(n, 0), b1 = rdB(n, 1);
      #pragma unroll
      for (int m = 0; m < 4; ++m) {
        f32x4 c = {0.f, 0.f, 0.f, 0.f};
        c = __builtin_amdgcn_mfma_f32_16x16x32_bf16(A[m][0], b0, c, 0, 0, 0);
        c = __builtin_amdgcn_mfma_f32_16x16x32_bf16(A[m][1], b1, c, 0, 0, 0);
        wrC(n, m * 16 + g * 4, c);
      }
    }
    MEMBAR();
  };

  layer64(wb + WBC0);
  layer64(wb + WBC1);
  layer64(wb + WBC2);

  {
    const u16* Wp = wb + WBC3;
    bf16x8 A0 = ldA(Wp, q, 0), A1 = ldA(Wp, q, 1);
    #pragma unroll
    for (int n = 0; n < 4; ++n) {
      bf16x8 b0 = rdB(n, 0), b1 = rdB(n, 1);
      f32x4 c = {0.f, 0.f, 0.f, 0.f};
      c = __builtin_amdgcn_mfma_f32_16x16x32_bf16(A0, b0, c, 0, 0, 0);
      c = __builtin_amdgcn_mfma_f32_16x16x32_bf16(A1, b1, c, 0, 0, 0);
      if (g == 0) {
        uint2 o; o.x = pack2(c[0], c[1]); o.y = pack2(c[2], sigv[n]);
        *(uint2*)(raw + (size_t)(pBase + n * 16 + q) * 4) = o;
      }
    }
  }
}

// ---------------- per-ray compositing (single merged pass) ----------------
__global__ void __launch_bounds__(64)
render_kernel(const float* __restrict__ rays, const u16* __restrict__ raw,
              float* __restrict__ out)
{
  const int r = blockIdx.x * 64 + threadIdx.x;
  if (r >= NRAYS) return;
  const float dx = rays[r * 7 + 3], dy = rays[r * 7 + 4], dz = rays[r * 7 + 5];
  const float nrm = sqrtf(dx * dx + dy * dy + dz * dz);
  const float dstep = 3.5f / 127.f;
  const ushort4* rp = reinterpret_cast<const ushort4*>(raw) + (size_t)r * NSAMP;

  float T = 1.f, sumw = 0.f, sumwz = 0.f, cm0 = 0.f, cm1 = 0.f, cm2 = 0.f;
  float S1 = 0.f, S2 = 0.f;
  for (int s = 0; s < NSAMP; ++s) {
    const ushort4 rw = rp[s];
    const float dist = ((s < NSAMP - 1) ? dstep : 1e10f) * nrm;
    const float sigv = fmaxf(b2f(rw.w), 0.f);
    const float alpha = 1.f - expf(-sigv * dist);
    const float wgt = alpha * T;
    T *= (1.f - alpha + 1e-10f);
    const float zv = 0.5f + dstep * (float)s;
    sumw += wgt;
    sumwz = fmaf(wgt, zv, sumwz);
    cm0 = fmaf(wgt, sigmoidf_(b2f(rw.x)), cm0);
    cm1 = fmaf(wgt, sigmoidf_(b2f(rw.y)), cm1);
    cm2 = fmaf(wgt, sigmoidf_(b2f(rw.z)), cm2);
    const float qv = fmaxf(wgt, 1e-12f);
    S1 += qv;
    S2 = fmaf(qv, logf(qv), S2);
  }
  const float plast = fmaxf(1.f - sumw + 1e-6f, 1e-12f);
  S1 += plast;
  S2 = fmaf(plast, logf(plast), S2);
  const float ent = logf(S1) - S2 / S1;

  out[r * 3 + 0] = cm0;
  out[r * 3 + 1] = cm1;
  out[r * 3 + 2] = cm2;
  out[NRAYS * 3 + r] = sumwz;
  out[NRAYS * 4 + r] = ent;
}

extern "C" void kernel_launch(void* const* d_in, const int* in_sizes, int n_in,
                              void* d_out, int out_size, void* d_ws, size_t ws_size,
                              hipStream_t stream)
{
  const float* rays   = (const float*)d_in[0];
  const float* tables = (const float*)d_in[2];
  const float* ws0    = (const float*)d_in[3];
  const float* ws1    = (const float*)d_in[4];
  const float* ws2    = (const float*)d_in[5];
  const float* wc0    = (const float*)d_in[6];
  const float* wc1    = (const float*)d_in[7];
  const float* wc2    = (const float*)d_in[8];
  const float* wc3    = (const float*)d_in[9];
  const float* app    = (const float*)d_in[10];

  u16* wb    = (u16*)d_ws;
  float* w2c0 = (float*)((char*)d_ws + W2C0_OFF);
  u16* raw   = (u16*)((char*)d_ws + RAW_OFF);
  float* out = (float*)d_out;

  ResArr RES;
  const double b = exp((log(512.0) - log(16.0)) / 15.0);
  for (int l = 0; l < 16; ++l) RES.r[l] = (float)floor(16.0 * pow(b, (double)l));

  hipLaunchKernelGGL(prep_kernel, dim3(8), dim3(256), 0, stream,
                     ws0, ws1, ws2, wc0, wc1, wc2, wc3, wb, w2c0);
  hipLaunchKernelGGL(point_kernel, dim3(NPTS / 64), dim3(64), 0, stream,
                     rays, tables, wb, w2c0, app, raw, RES);
  hipLaunchKernelGGL(render_kernel, dim3(NRAYS / 64), dim3(64), 0, stream,
                     rays, raw, out);
}

// Round 11
// 296.106 us; speedup vs baseline: 1.0896x; 1.0896x over previous
//
#include <hip/hip_runtime.h>
#include <math.h>

typedef unsigned short u16;
typedef short bf16x8 __attribute__((ext_vector_type(8)));
typedef float f32x4 __attribute__((ext_vector_type(4)));

#define NRAYS 4096
#define NSAMP 128
#define NPTS (NRAYS * NSAMP)
#define TBL_MASK 0x7FFFFu
#define LVL_STRIDE (524288 * 2)

// d_ws layout (u16 elem offsets): color weights only, then raw
#define WB_C0 0        // [64][64] rows: 0..15 encd, 16 dead(sigma), 17..31 geo, 32..47 app, 48..63 zero
#define WB_C1 4096
#define WB_C2 8192
#define WB_C3 12288    // [16][64] rows 0..2 = color
#define RAW_OFF 65536  // bf16x4 per point: 4 MB

#define MEMBAR() asm volatile("" ::: "memory")

struct ResArr { float r[16]; };

__device__ __forceinline__ u16 f2b(float f) {   // RNE f32->bf16
  unsigned u = __float_as_uint(f);
  unsigned r = u + 0x7FFFu + ((u >> 16) & 1u);
  return (u16)(r >> 16);
}
__device__ __forceinline__ unsigned pack2(float lo, float hi) {
  return (unsigned)f2b(lo) | ((unsigned)f2b(hi) << 16);
}
__device__ __forceinline__ float b2f(u16 u) {
  return __uint_as_float(((unsigned)u) << 16);
}
__device__ __forceinline__ float sigmoidf_(float x) { return 1.f / (1.f + expf(-x)); }

// scalar f32 layer, CH=16 output chunks to cap VGPR peak (~130 with in[64]).
// Weight addresses are wave-uniform -> scalar loads; FMAs pair into v_pk_fma_f32.
template<int IN, int OUT>
__device__ __forceinline__ void layer(const float (&in)[IN], float (&out)[OUT],
                                      const float* __restrict__ W, bool dorelu)
{
  constexpr int CH = (OUT < 16) ? OUT : 16;
  #pragma unroll
  for (int oc = 0; oc < OUT; oc += CH) {
    float acc[CH];
    #pragma unroll
    for (int o = 0; o < CH; ++o) acc[o] = 0.f;
    #pragma unroll
    for (int i = 0; i < IN; ++i) {
      const float x = in[i];
      const float* wr = W + i * OUT + oc;
      #pragma unroll
      for (int o = 0; o < CH; ++o) acc[o] = fmaf(x, wr[o], acc[o]);
    }
    #pragma unroll
    for (int o = 0; o < CH; ++o) out[oc + o] = dorelu ? fmaxf(acc[o], 0.f) : acc[o];
  }
}

// ---------------- prep: probe MFMA k-pairing + pack color weights (8 blocks) ----------------
__global__ void __launch_bounds__(256)
prep_kernel(const float* __restrict__ wc0, const float* __restrict__ wc1,
            const float* __restrict__ wc2, const float* __restrict__ wc3,
            u16* __restrict__ wb)
{
  __shared__ int P[32];
  __shared__ int Pinv[32];
  const int t = threadIdx.x;
  if (t < 64) {
    const int g = t >> 4;
    for (int tt = 0; tt < 32; ++tt) {
      bf16x8 A, B;
      #pragma unroll
      for (int e = 0; e < 8; ++e) {
        A[e] = (short)f2b((float)(g * 8 + e + 1));
        B[e] = (short)((g * 8 + e == tt) ? 0x3F80 : 0);   // bf16(1.0)
      }
      f32x4 c = {0.f, 0.f, 0.f, 0.f};
      c = __builtin_amdgcn_mfma_f32_16x16x32_bf16(A, B, c, 0, 0, 0);
      if (t == 0) P[tt] = (int)(c[0] + 0.5f) - 1;
    }
  }
  __syncthreads();
  if (t < 32) Pinv[t] = t;
  __syncthreads();
  if (t < 32) { int p = P[t]; if (p >= 0 && p < 32) Pinv[p] = t; }
  __syncthreads();

  const int gt = blockIdx.x * 256 + t;
  const int GS = 8 * 256;
  // color layer 0 rows: kt<16 -> encd; 16 dead; 17..47 -> wc0 rows 16..46; else 0
  for (int i = gt; i < 4096; i += GS) {
    int o = i >> 6, s6 = i & 63, kt = (s6 & 32) | Pinv[s6 & 31];
    float v = 0.f;
    if (kt < 16) v = wc0[kt * 64 + o];
    else if (kt >= 17 && kt <= 47) v = wc0[(kt - 1) * 64 + o];
    wb[WB_C0 + i] = f2b(v);
  }
  for (int i = gt; i < 4096; i += GS) {
    int o = i >> 6, s6 = i & 63, kt = (s6 & 32) | Pinv[s6 & 31];
    wb[WB_C1 + i] = f2b(wc1[kt * 64 + o]);
  }
  for (int i = gt; i < 4096; i += GS) {
    int o = i >> 6, s6 = i & 63, kt = (s6 & 32) | Pinv[s6 & 31];
    wb[WB_C2 + i] = f2b(wc2[kt * 64 + o]);
  }
  for (int i = gt; i < 1024; i += GS) {
    int o = i >> 6, s6 = i & 63, kt = (s6 & 32) | Pinv[s6 & 31];
    wb[WB_C3 + i] = f2b(o < 3 ? wc3[kt * 3 + o] : 0.f);
  }
}

// ---------------- fused encode + f32 scalar sigma MLP + bf16 MFMA color MLP ----------------
// R4 structure (222us, proven): 4 waves/block, wave-private 8KB LDS, scalar
// sigma (issue-bound -> overlaps gather latency; beats the LDS-round-trip
// MFMA sigma at 4 waves/SIMD). R4 defect fixed: waves_per_eu(2,4) lets the
// allocator keep natural pressure (R4's launch_bounds squeezed to 64 VGPR ->
// 26MB spill). CH=16 layer chunks cap peak at ~130 VGPR.
__global__ __attribute__((amdgpu_flat_work_group_size(256, 256), amdgpu_waves_per_eu(2, 4)))
void point_kernel(const float* __restrict__ rays, const float* __restrict__ tables,
                  const float* __restrict__ ws0, const float* __restrict__ ws1,
                  const float* __restrict__ ws2, const u16* __restrict__ wb,
                  const float* __restrict__ app_table, u16* __restrict__ raw, ResArr RES)
{
  __shared__ char lds[4 * 8192 + 4 * 256];
  const int t = threadIdx.x, wv = t >> 6, lane = t & 63;
  char* buf = lds + wv * 8192;
  float* sigb = (float*)(lds + 32768 + wv * 256);
  const int pBase = blockIdx.x * 256 + wv * 64;
  const int q = lane & 15, g = lane >> 4;
  const unsigned fswz = (unsigned)((q & 7) << 4);
  const unsigned myswz = (unsigned)((lane & 7) << 4);

  // ---------- phase 1: per-thread encode + scalar f32 sigma MLP ----------
  const int ptG = pBase + lane;
  const int r = ptG >> 7, s = ptG & (NSAMP - 1);
  const float ox = rays[r * 7 + 0], oy = rays[r * 7 + 1], oz = rays[r * 7 + 2];
  const float dx = rays[r * 7 + 3], dy = rays[r * 7 + 4], dz = rays[r * 7 + 5];
  const int code = (int)rays[r * 7 + 6];
  const float z = 0.5f + (3.5f / 127.f) * (float)s;
  const float x = fmaf(dx, z, ox), y = fmaf(dy, z, oy), w = fmaf(dz, z, oz);
  const bool keep = (x >= -4.f && x <= 4.f && y >= -4.f && y <= 4.f &&
                     w >= -4.f && w <= 4.f);
  const float xc = fminf(fmaxf(x, -4.f), 4.f);
  const float yc = fminf(fmaxf(y, -4.f), 4.f);
  const float zc = fminf(fmaxf(w, -4.f), 4.f);

  float encp[32];
  #pragma unroll
  for (int l = 0; l < 16; ++l) {
    const float res = RES.r[l];
    const float sc = res * 0.125f;
    const float px = (xc + 4.f) * sc, py = (yc + 4.f) * sc, pz = (zc + 4.f) * sc;
    const float bx = floorf(px), by = floorf(py), bz = floorf(pz);
    const float fx = px - bx, fy = py - by, fz = pz - bz;
    const unsigned ix = (unsigned)bx, iy = (unsigned)by, iz = (unsigned)bz;
    const unsigned hx0 = ix, hx1 = ix + 1u;
    const unsigned hy0 = iy * 2654435761u, hy1 = (iy + 1u) * 2654435761u;
    const unsigned hz0 = iz * 805459861u,  hz1 = (iz + 1u) * 805459861u;
    const float wx0 = 1.f - fx, wy0 = 1.f - fy, wz0 = 1.f - fz;
    const float* tl = tables + (size_t)l * LVL_STRIDE;
    float f0 = 0.f, f1 = 0.f;
    #pragma unroll
    for (int c = 0; c < 8; ++c) {
      const unsigned cx = (c >> 2) & 1, cy = (c >> 1) & 1, cz = c & 1;
      const unsigned idx = ((cx ? hx1 : hx0) ^ (cy ? hy1 : hy0) ^ (cz ? hz1 : hz0)) & TBL_MASK;
      const float cw = (cx ? fx : wx0) * (cy ? fy : wy0) * (cz ? fz : wz0);
      const float2 e = *reinterpret_cast<const float2*>(tl + (size_t)idx * 2);
      f0 = fmaf(cw, e.x, f0);
      f1 = fmaf(cw, e.y, f1);
    }
    encp[2 * l] = f0;
    encp[2 * l + 1] = f1;
  }

  // sigma MLP fully in f32 (round-1/round-4-proven)
  float h1[64]; layer<32, 64>(encp, h1, ws0, true);
  float h2[64]; layer<64, 64>(h1, h2, ws1, true);
  float gg[16]; layer<64, 16>(h2, gg, ws2, false);
  sigb[lane] = keep ? gg[0] : 0.f;

  // color input row: slots 0..15 encd, 16..30 geo, 31..46 app, 47..63 zero
  {
    float cin[64];
    const float xx = dx * dx, yy = dy * dy, zz2 = dz * dz;
    const float xy = dx * dy, yz = dy * dz, xz = dx * dz;
    cin[0]  = 0.28209479177387814f;
    cin[1]  = -0.4886025119029199f * dy;
    cin[2]  = 0.4886025119029199f * dz;
    cin[3]  = -0.4886025119029199f * dx;
    cin[4]  = 1.0925484305920792f * xy;
    cin[5]  = -1.0925484305920792f * yz;
    cin[6]  = 0.31539156525252005f * (2.f * zz2 - xx - yy);
    cin[7]  = -1.0925484305920792f * xz;
    cin[8]  = 0.5462742152960396f * (xx - yy);
    cin[9]  = -0.5900435899266435f * dy * (3.f * xx - yy);
    cin[10] = 2.890611442640554f * xy * dz;
    cin[11] = -0.4570457994644658f * dy * (4.f * zz2 - xx - yy);
    cin[12] = 0.3731763325901154f * dz * (2.f * zz2 - 3.f * xx - 3.f * yy);
    cin[13] = -0.4570457994644658f * dx * (4.f * zz2 - xx - yy);
    cin[14] = 1.445305721320277f * dz * (xx - yy);
    cin[15] = -0.5900435899266435f * dx * (xx - 3.f * yy);
    #pragma unroll
    for (int i = 0; i < 15; ++i) cin[16 + i] = gg[1 + i];
    const float4* ap = (const float4*)(app_table + (size_t)code * 16);
    float4 a0 = ap[0], a1 = ap[1], a2 = ap[2], a3 = ap[3];
    cin[31] = a0.x; cin[32] = a0.y; cin[33] = a0.z; cin[34] = a0.w;
    cin[35] = a1.x; cin[36] = a1.y; cin[37] = a1.z; cin[38] = a1.w;
    cin[39] = a2.x; cin[40] = a2.y; cin[41] = a2.z; cin[42] = a2.w;
    cin[43] = a3.x; cin[44] = a3.y; cin[45] = a3.z; cin[46] = a3.w;
    #pragma unroll
    for (int i = 47; i < 64; ++i) cin[i] = 0.f;
    #pragma unroll
    for (int c = 0; c < 8; ++c) {
      uint4 u;
      u.x = pack2(cin[8 * c + 0], cin[8 * c + 1]);
      u.y = pack2(cin[8 * c + 2], cin[8 * c + 3]);
      u.z = pack2(cin[8 * c + 4], cin[8 * c + 5]);
      u.w = pack2(cin[8 * c + 6], cin[8 * c + 7]);
      *(uint4*)(buf + lane * 128 + (((unsigned)(c * 16)) ^ myswz)) = u;
    }
  }
  MEMBAR();   // pack stores -> c0 loads

  // ---------- phase 2: color MFMA MLP (wave-private, no barriers; R4-proven) ----------
  auto rdB = [&](int n, int kc) -> bf16x8 {
    return *(const bf16x8*)(buf + (n * 16 + q) * 128 + (((unsigned)(kc * 64 + g * 16)) ^ fswz));
  };
  auto ldA = [&](const u16* Wp, int row, int kc) -> bf16x8 {
    return *(const bf16x8*)(Wp + row * 64 + kc * 32 + g * 8);
  };
  auto wrC = [&](int n, int slot0, f32x4 c) {
    c[0] = fmaxf(c[0], 0.f); c[1] = fmaxf(c[1], 0.f);
    c[2] = fmaxf(c[2], 0.f); c[3] = fmaxf(c[3], 0.f);
    uint2 u; u.x = pack2(c[0], c[1]); u.y = pack2(c[2], c[3]);
    *(uint2*)(buf + (n * 16 + q) * 128 + (((unsigned)(slot0 * 2)) ^ fswz)) = u;
  };
  auto layer64 = [&](const u16* Wp) {
    bf16x8 A[4][2];
    #pragma unroll
    for (int m = 0; m < 4; ++m) {
      A[m][0] = ldA(Wp, m * 16 + q, 0);
      A[m][1] = ldA(Wp, m * 16 + q, 1);
    }
    #pragma unroll
    for (int n = 0; n < 4; ++n) {
      bf16x8 b0 = rdB(n, 0), b1 = rdB(n, 1);
      #pragma unroll
      for (int m = 0; m < 4; ++m) {
        f32x4 c = f32x4{0.f, 0.f, 0.f, 0.f};
        c = __builtin_amdgcn_mfma_f32_16x16x32_bf16(A[m][0], b0, c, 0, 0, 0);
        c = __builtin_amdgcn_mfma_f32_16x16x32_bf16(A[m][1], b1, c, 0, 0, 0);
        wrC(n, m * 16 + g * 4, c);
      }
    }
    MEMBAR();
  };

  layer64(wb + WB_C0);  // c0
  layer64(wb + WB_C1);  // c1
  layer64(wb + WB_C2);  // c2

  // c3: 64 -> 3 colors (+ f32-path sigma) -> global raw (bf16x4 per point)
  {
    const u16* Wp = wb + WB_C3;
    bf16x8 A0 = ldA(Wp, q, 0), A1 = ldA(Wp, q, 1);
    #pragma unroll
    for (int n = 0; n < 4; ++n) {
      bf16x8 b0 = rdB(n, 0), b1 = rdB(n, 1);
      f32x4 c = f32x4{0.f, 0.f, 0.f, 0.f};
      c = __builtin_amdgcn_mfma_f32_16x16x32_bf16(A0, b0, c, 0, 0, 0);
      c = __builtin_amdgcn_mfma_f32_16x16x32_bf16(A1, b1, c, 0, 0, 0);
      if (g == 0) {
        uint2 o; o.x = pack2(c[0], c[1]); o.y = pack2(c[2], sigb[n * 16 + q]);
        *(uint2*)(raw + (size_t)(pBase + n * 16 + q) * 4) = o;
      }
    }
  }
}

// ---------------- per-ray compositing (single merged pass, proven R8-R10) ----------------
__global__ void __launch_bounds__(64)
render_kernel(const float* __restrict__ rays, const u16* __restrict__ raw,
              float* __restrict__ out)
{
  const int r = blockIdx.x * 64 + threadIdx.x;
  if (r >= NRAYS) return;
  const float dx = rays[r * 7 + 3], dy = rays[r * 7 + 4], dz = rays[r * 7 + 5];
  const float nrm = sqrtf(dx * dx + dy * dy + dz * dz);
  const float dstep = 3.5f / 127.f;
  const ushort4* rp = reinterpret_cast<const ushort4*>(raw) + (size_t)r * NSAMP;

  float T = 1.f, sumw = 0.f, sumwz = 0.f, cm0 = 0.f, cm1 = 0.f, cm2 = 0.f;
  float S1 = 0.f, S2 = 0.f;
  for (int s = 0; s < NSAMP; ++s) {
    const ushort4 rw = rp[s];
    const float dist = ((s < NSAMP - 1) ? dstep : 1e10f) * nrm;
    const float sigv = fmaxf(b2f(rw.w), 0.f);
    const float alpha = 1.f - expf(-sigv * dist);
    const float wgt = alpha * T;
    T *= (1.f - alpha + 1e-10f);
    const float zv = 0.5f + dstep * (float)s;
    sumw += wgt;
    sumwz = fmaf(wgt, zv, sumwz);
    cm0 = fmaf(wgt, sigmoidf_(b2f(rw.x)), cm0);
    cm1 = fmaf(wgt, sigmoidf_(b2f(rw.y)), cm1);
    cm2 = fmaf(wgt, sigmoidf_(b2f(rw.z)), cm2);
    const float qv = fmaxf(wgt, 1e-12f);
    S1 += qv;
    S2 = fmaf(qv, logf(qv), S2);
  }
  const float plast = fmaxf(1.f - sumw + 1e-6f, 1e-12f);
  S1 += plast;
  S2 = fmaf(plast, logf(plast), S2);
  const float ent = logf(S1) - S2 / S1;

  out[r * 3 + 0] = cm0;
  out[r * 3 + 1] = cm1;
  out[r * 3 + 2] = cm2;
  out[NRAYS * 3 + r] = sumwz;
  out[NRAYS * 4 + r] = ent;
}

extern "C" void kernel_launch(void* const* d_in, const int* in_sizes, int n_in,
                              void* d_out, int out_size, void* d_ws, size_t ws_size,
                              hipStream_t stream)
{
  const float* rays   = (const float*)d_in[0];
  const float* tables = (const float*)d_in[2];
  const float* ws0    = (const float*)d_in[3];
  const float* ws1    = (const float*)d_in[4];
  const float* ws2    = (const float*)d_in[5];
  const float* wc0    = (const float*)d_in[6];
  const float* wc1    = (const float*)d_in[7];
  const float* wc2    = (const float*)d_in[8];
  const float* wc3    = (const float*)d_in[9];
  const float* app    = (const float*)d_in[10];

  u16* wb  = (u16*)d_ws;
  u16* raw = (u16*)((char*)d_ws + RAW_OFF);
  float* out = (float*)d_out;

  ResArr RES;
  const double b = exp((log(512.0) - log(16.0)) / 15.0);
  for (int l = 0; l < 16; ++l) RES.r[l] = (float)floor(16.0 * pow(b, (double)l));

  hipLaunchKernelGGL(prep_kernel, dim3(8), dim3(256), 0, stream,
                     wc0, wc1, wc2, wc3, wb);
  hipLaunchKernelGGL(point_kernel, dim3(NPTS / 256), dim3(256), 0, stream,
                     rays, tables, ws0, ws1, ws2, wb, app, raw, RES);
  hipLaunchKernelGGL(render_kernel, dim3(NRAYS / 64), dim3(64), 0, stream,
                     rays, raw, out);
}